// Round 18
// baseline (399.856 us; speedup 1.0000x reference)
//
#include <hip/hip_runtime.h>
#include <math.h>

#define B_   4
#define EC_  32
#define E_   48
#define S_   2048
#define F_   128

typedef __attribute__((ext_vector_type(2)))  float f32x2;
typedef __attribute__((ext_vector_type(8)))  short short8;
typedef __attribute__((ext_vector_type(4)))  float f32x4;
typedef __attribute__((ext_vector_type(16))) float f32x16;

// A1: GEMM1 weights (rfc1_w) as 32x32x16 A-fragments (transposed GEMM):
//   f_out = MT*32 + (lane&31)
//   f_in  = (ks>>1)*32 + (ks&1)*16 + ((j>>2)&1)*8 + (j&3) + (lane>>5)*4
__device__ __align__(16) short g_A1[4 * 8 * 64 * 8];     // 32 KB

// per-be park: [0..127]=gamma2', [128..255]=beta2', [256..383]=u,
// [384..399]=geo, [400..403]=w3c, [416..1439]=A0 frags (2048 shorts)
#define PKF2 1440
__device__ __align__(16) float g_bepark[B_ * E_ * PKF2];

// monotonic grid-barrier counter (never reset; target = next multiple of 768)
__device__ unsigned g_arrive;

static __device__ __forceinline__ short f2bf(float x) {
    unsigned u = __float_as_uint(x);
    unsigned r = (u + 0x7FFFu + ((u >> 16) & 1u)) >> 16;   // RNE
    return (short)r;
}

static __device__ __forceinline__ f32x2 pkfma(f32x2 a, f32x2 b, f32x2 c) {
    f32x2 d;
    asm("v_pk_fma_f32 %0, %1, %2, %3" : "=v"(d) : "v"(a), "v"(b), "v"(c));
    return d;
}

// ---------------------------------------------------------------------------
// Single fused kernel. grid = 768 x 256 (exactly 3 blocks/CU co-resident by
// __launch_bounds__(256,3); LDS 38.5KB allows 4/CU so VGPR is the binder).
// Phase 1: blocks 0..191 precompute; 192..199 A1 pack; 200..203 zero out
//          (atomicExch -> coherent point, safe vs phase-2 atomics).
// Software grid barrier (monotonic counter, device-scope atomics).
// Phase 2: all 768 blocks run the R12 main body (4 waves, 4 elements each).
// ---------------------------------------------------------------------------
__global__ __launch_bounds__(256, 3) void ldif_fused(
    const float* __restrict__ packed, const float* __restrict__ samples,
    const float* __restrict__ fc1w, const float* __restrict__ fc1b,
    const float* __restrict__ bw1, const float* __restrict__ bb1,
    const float* __restrict__ gw1, const float* __restrict__ gb1,
    const float* __restrict__ rb1g, const float* __restrict__ rw1,
    const float* __restrict__ bw2, const float* __restrict__ bb2,
    const float* __restrict__ gw2, const float* __restrict__ gb2,
    const float* __restrict__ rw2, const float* __restrict__ rb2g,
    const float* __restrict__ bw3, const float* __restrict__ bb3,
    const float* __restrict__ gw3, const float* __restrict__ gb3,
    const float* __restrict__ fc2w, const float* __restrict__ fc2b,
    float* __restrict__ out)
{
    __shared__ __align__(16) short lsA1[4 * 8 * 64 * 8];   // 32 KB (ph1 overlay)
    __shared__ __align__(16) float lsPar[4 * 416];         // 6.5 KB

    const int bid = blockIdx.x;
    const int tid = threadIdx.x;

    // ================== PHASE 1 ==================
    if (bid < 192) {
        const int be = bid;
        const int b  = be / E_;
        const int e  = be - b * E_;
        const int ec = (e < EC_) ? e : (e - EC_);
        const float* pv = packed + (size_t)(b * EC_ + ec) * 138;
        float* P = g_bepark + (size_t)be * PKF2;

        float* shf  = (float*)lsA1;           // overlay: 1802 floats < 32 KB
        float* emb  = shf;                    // 128
        float* part = shf + 128;              // [6][2][128]
        float* g3s  = shf + 128 + 1536;       // 128
        float* wred = shf + 1792;             // [2][5]

        const int t = tid & 127;
        const int h = tid >> 7;               // 0..1 (k-half)
        if (h == 0) emb[t] = pv[10 + t];
        __syncthreads();

        float a0 = 0.f, a1 = 0.f, a2 = 0.f, a3 = 0.f, a4 = 0.f, a5 = 0.f;
        for (int k = h * 64; k < h * 64 + 64; ++k) {
            const float ek = emb[k];
            a0 = fmaf(ek, bw1[k * F_ + t], a0);
            a1 = fmaf(ek, gw1[k * F_ + t], a1);
            a2 = fmaf(ek, bw2[k * F_ + t], a2);
            a3 = fmaf(ek, gw2[k * F_ + t], a3);
            a4 = fmaf(ek, bw3[k * F_ + t], a4);
            a5 = fmaf(ek, gw3[k * F_ + t], a5);
        }
        part[(0 * 2 + h) * 128 + t] = a0;
        part[(1 * 2 + h) * 128 + t] = a1;
        part[(2 * 2 + h) * 128 + t] = a2;
        part[(3 * 2 + h) * 128 + t] = a3;
        part[(4 * 2 + h) * 128 + t] = a4;
        part[(5 * 2 + h) * 128 + t] = a5;
        __syncthreads();

        const float inv = 0.99999500003749984f;   // 1/sqrt(1+1e-5)
        if (h == 0) {
            const float sb1 = part[0 * 128 + t]  + part[1 * 128 + t];
            const float sg1 = part[2 * 128 + t]  + part[3 * 128 + t];
            const float sb2 = part[4 * 128 + t]  + part[5 * 128 + t];
            const float sg2 = part[6 * 128 + t]  + part[7 * 128 + t];
            const float sb3 = part[8 * 128 + t]  + part[9 * 128 + t];
            const float sg3 = part[10 * 128 + t] + part[11 * 128 + t];

            const float g1p = (sg1 + gb1[t]) * inv;
            const float b1  =  sb1 + bb1[t];
            const float g2p = (sg2 + gb2[t]) * inv;
            const float b2p = fmaf(g2p, rb1g[t], sb2 + bb2[t]);   // rb1 folded
            const float g3  = (sg3 + gb3[t]) * inv * fc2w[t];     // fc2 folded

            P[0 * F_ + t] = g2p;
            P[1 * F_ + t] = b2p;
            g3s[t] = g3;

            // A0 fragment (fc1 + CBN1 folded)
            const float w0p = g1p * fc1w[t];
            const float w1p = g1p * fc1w[F_ + t];
            const float w2p = g1p * fc1w[2 * F_ + t];
            const float pbp = fmaf(g1p, fc1b[t], b1);
            short* A0 = (short*)(P + 416);
            const int MTl = t >> 5, fl = t & 31;
            short8 v  = {f2bf(w0p), f2bf(w1p), f2bf(w2p), f2bf(pbp), 0, 0, 0, 0};
            short8 zz = {0, 0, 0, 0, 0, 0, 0, 0};
            *(short8*)&A0[(MTl * 64 + fl) * 8]      = v;
            *(short8*)&A0[(MTl * 64 + 32 + fl) * 8] = zz;

            // 2-wave shfl reduction of cbeta & w3 partials (exact fp32 fold)
            float cbv  = (sb3 + bb3[t]) * fc2w[t] + g3 * rb2g[t];
            float w30v = g3 * w0p;
            float w31v = g3 * w1p;
            float w32v = g3 * w2p;
            float w3bv = g3 * pbp;
            #pragma unroll
            for (int off = 32; off >= 1; off >>= 1) {
                cbv  += __shfl_xor(cbv,  off);
                w30v += __shfl_xor(w30v, off);
                w31v += __shfl_xor(w31v, off);
                w32v += __shfl_xor(w32v, off);
                w3bv += __shfl_xor(w3bv, off);
            }
            if ((t & 63) == 0) {
                const int wv = t >> 6;
                wred[wv * 5 + 0] = cbv;  wred[wv * 5 + 1] = w30v;
                wred[wv * 5 + 2] = w31v; wred[wv * 5 + 3] = w32v;
                wred[wv * 5 + 4] = w3bv;
            }
        } else if (tid == 128) {
            // geometry (concurrent with the h==0 fold section)
            const float sx = fmaxf(pv[4], 1e-4f);
            const float sy = fmaxf(pv[5], 1e-4f);
            const float sz = fmaxf(pv[6], 1e-4f);
            const float ar = pv[7], ap = pv[8], ay = pv[9];
            const float cr = cosf(ar), sr = sinf(ar);
            const float cp = cosf(ap), sp = sinf(ap);
            const float cyw = cosf(ay), syw = sinf(ay);
            float* g = P + 384;
            g[0] = pv[0]; g[1] = pv[1]; g[2] = pv[2]; g[3] = pv[3];
            g[4] = 1.f / sx; g[5] = 1.f / sy; g[6] = 1.f / sz;
            g[7]  = cyw * cp;  g[8]  = cyw * sp * sr - syw * cr;  g[9]  = cyw * sp * cr + syw * sr;
            g[10] = syw * cp;  g[11] = syw * sp * sr + cyw * cr;  g[12] = syw * sp * cr - cyw * sr;
            g[13] = -sp;       g[14] = cp * sr;                   g[15] = cp * cr;
        }
        __syncthreads();

        // u[k] = sum_f g3[f] * rw2[k][f]  (f-dim split over h halves)
        {
            float ua = 0.f;
            const float* wrow = rw2 + (size_t)t * F_ + h * 64;
            #pragma unroll
            for (int f4 = 0; f4 < 64; f4 += 4) {
                const f32x4 wv = *(const f32x4*)&wrow[f4];
                const int fb = h * 64 + f4;
                ua = fmaf(wv[0], g3s[fb + 0], ua);
                ua = fmaf(wv[1], g3s[fb + 1], ua);
                ua = fmaf(wv[2], g3s[fb + 2], ua);
                ua = fmaf(wv[3], g3s[fb + 3], ua);
            }
            __syncthreads();              // folds done with part before reuse
            part[h * 128 + t] = ua;
        }
        __syncthreads();

        if (h == 0)
            P[2 * F_ + t] = part[t] + part[128 + t];

        if (tid == 0) {
            P[400] = wred[1] + wred[6];
            P[401] = wred[2] + wred[7];
            P[402] = wred[3] + wred[8];
            P[403] = (wred[4] + wred[9]) + fc2b[0] + wred[0] + wred[5];
        }
    } else if (bid < 200) {               // ---- A1 packing: 4 units/block ----
        const int unit = (bid - 192) * 4 + (tid >> 6);   // 0..31
        const int l  = tid & 63;
        const int MT = unit >> 3;
        const int ks = unit & 7;
        const int fo = MT * 32 + (l & 31);
        const int q1 = l >> 5;
        short8 v;
        #pragma unroll
        for (int j = 0; j < 8; ++j) {
            const int fi = (ks >> 1) * 32 + (ks & 1) * 16 + ((j >> 2) & 1) * 8 +
                           (j & 3) + q1 * 4;
            v[j] = f2bf(rw1[fi * F_ + fo]);
        }
        *(short8*)&g_A1[((MT * 8 + ks) * 64 + l) * 8] = v;
    } else if (bid < 204) {               // ---- zero d_out via atomicExch ----
        float* o = out + (size_t)(bid - 200) * 2048 + tid * 8;
        #pragma unroll
        for (int j = 0; j < 8; ++j) atomicExch(&o[j], 0.f);
    }

    // ================== software grid barrier ==================
    __threadfence();                      // flush phase-1 writes device-wide
    __syncthreads();
    if (tid == 0) {
        const unsigned prev = __hip_atomic_fetch_add(
            &g_arrive, 1u, __ATOMIC_RELEASE, __HIP_MEMORY_SCOPE_AGENT);
        const unsigned target = (prev / 768u + 1u) * 768u;
        while (__hip_atomic_load(&g_arrive, __ATOMIC_ACQUIRE,
                                 __HIP_MEMORY_SCOPE_AGENT) < target)
            __builtin_amdgcn_s_sleep(8);
    }
    __syncthreads();
    __threadfence();

    // ================== PHASE 2 (R12 main) ==================
    const int eq  = bid % 12;
    const int r12 = bid / 12;
    const int seg = r12 & 15;
    const int b   = r12 >> 4;

    // ---- stage A1 (32 KB) + 4 elements' params into LDS ----
    {
        const f32x4* src = (const f32x4*)g_A1;
        f32x4* dst = (f32x4*)lsA1;
        #pragma unroll
        for (int i = 0; i < 8; ++i) dst[i * 256 + tid] = src[i * 256 + tid];
    }
    for (int i = tid; i < 416; i += 256) {
        const int ei = i / 104;
        const int o4 = i - ei * 104;
        ((f32x4*)lsPar)[ei * 104 + o4] =
            *(const f32x4*)&g_bepark[(size_t)(b * E_ + eq * 4 + ei) * PKF2 + o4 * 4];
    }
    __syncthreads();

    const int w   = tid >> 6;
    const int l   = tid & 63;
    const int q1  = l >> 5;
    const int l31 = l & 31;
    const int sidx = seg * 128 + w * 32 + l31;
    const f32x16 z16 = {0.f,0.f,0.f,0.f,0.f,0.f,0.f,0.f,
                        0.f,0.f,0.f,0.f,0.f,0.f,0.f,0.f};

    const float* sp = samples + ((size_t)b * S_ + sidx) * 3;
    const float xs = sp[0], ys = sp[1], zs0 = sp[2];

    float acc = 0.f;

    for (int ee = 0; ee < 4; ++ee) {
        const int e  = eq * 4 + ee;
        const int be = b * E_ + e;
        const float* Pl = &lsPar[ee * 416];
        const float* gg = Pl + 384;
        const float* w3 = Pl + 400;
        const float* Pg = g_bepark + (size_t)be * PKF2;   // A0 frags only

        // ---- geometry ----
        float cwgt, sval;
        union { short8 s8; unsigned u[4]; } b0u;
        b0u.u[0] = 0; b0u.u[1] = 0; b0u.u[2] = 0; b0u.u[3] = 0;
        {
            const float zz = (e >= EC_) ? -zs0 : zs0;
            const float dx = xs - gg[1], dy = ys - gg[2], dz = zz - gg[3];
            const float l0 = (dx * gg[7] + dy * gg[10] + dz * gg[13]) * gg[4];
            const float l1 = (dx * gg[8] + dy * gg[11] + dz * gg[14]) * gg[5];
            const float l2 = (dx * gg[9] + dy * gg[12] + dz * gg[15]) * gg[6];
            cwgt = gg[0] * __expf(-0.5f * (l0 * l0 + l1 * l1 + l2 * l2));
            sval = fmaf(l0, w3[0], fmaf(l1, w3[1], fmaf(l2, w3[2], w3[3])));
            if (q1 == 0) {
                const float one = 1.0f;
                unsigned p01, p23;
                asm("v_cvt_pk_bf16_f32 %0, %1, %2" : "=v"(p01) : "v"(l0), "v"(l1));
                asm("v_cvt_pk_bf16_f32 %0, %1, %2" : "=v"(p23) : "v"(l2), "v"(one));
                b0u.u[0] = p01; b0u.u[1] = p23;
            }
        }
        const short8 b0 = b0u.s8;

        // ---- fc1+CBN1 MFMA interleaved with GEMM1 (early-d0-death) ----
        const short* A0g = (const short*)(Pg + 416);
        f32x16 d1[4];
        #pragma unroll
        for (int MT = 0; MT < 4; ++MT) d1[MT] = z16;

        #pragma unroll
        for (int MTs = 0; MTs < 4; ++MTs) {
            const short8 a0 = *(const short8*)&A0g[(MTs * 64 + l) * 8];
            const f32x16 d0 = __builtin_amdgcn_mfma_f32_32x32x16_bf16(a0, b0, z16, 0, 0, 0);
            #pragma unroll
            for (int kk = 0; kk < 2; ++kk) {
                const int ks = MTs * 2 + kk;
                union { short8 s8; unsigned u[4]; } b1u;
                #pragma unroll
                for (int jj = 0; jj < 4; ++jj) {
                    const int j0 = jj * 2;
                    const int r0 = (j0 & 3) + 4 * ((j0 >> 2) & 1) + 8 * kk;
                    const float v0 = fmaxf(d0[r0], 0.f);
                    const float v1 = fmaxf(d0[r0 + 1], 0.f);
                    asm("v_cvt_pk_bf16_f32 %0, %1, %2" : "=v"(b1u.u[jj]) : "v"(v0), "v"(v1));
                }
                const short8 b1 = b1u.s8;
                #pragma unroll
                for (int MT = 0; MT < 4; ++MT) {
                    const short8 a = *(const short8*)&lsA1[((MT * 8 + ks) * 64 + l) * 8];
                    d1[MT] = __builtin_amdgcn_mfma_f32_32x32x16_bf16(a, b1, d1[MT], 0, 0, 0);
                }
            }
        }

        // ---- epilogue: sum_k relu(g2*d1+b2')*u via pk_fma ----
        f32x2 partA = {0.f, 0.f};
        f32x2 partB = {0.f, 0.f};
        #pragma unroll
        for (int MT = 0; MT < 4; ++MT) {
            #pragma unroll
            for (int c = 0; c < 4; ++c) {
                const int fb = MT * 32 + c * 8 + q1 * 4;
                const f32x4 g2 = *(const f32x4*)&Pl[fb];
                const f32x4 b2 = *(const f32x4*)&Pl[128 + fb];
                const f32x4 uu = *(const f32x4*)&Pl[256 + fb];
                f32x2 g2a = {g2[0], g2[1]}, g2b = {g2[2], g2[3]};
                f32x2 b2a = {b2[0], b2[1]}, b2b = {b2[2], b2[3]};
                f32x2 uua = {uu[0], uu[1]}, uub = {uu[2], uu[3]};
                f32x2 d1a = {d1[MT][c * 4 + 0], d1[MT][c * 4 + 1]};
                f32x2 d1b = {d1[MT][c * 4 + 2], d1[MT][c * 4 + 3]};
                f32x2 tta = pkfma(g2a, d1a, b2a);
                f32x2 ttb = pkfma(g2b, d1b, b2b);
                tta[0] = fmaxf(tta[0], 0.f); tta[1] = fmaxf(tta[1], 0.f);
                ttb[0] = fmaxf(ttb[0], 0.f); ttb[1] = fmaxf(ttb[1], 0.f);
                partA = pkfma(tta, uua, partA);
                partB = pkfma(ttb, uub, partB);
            }
        }
        const float part = (partA[0] + partA[1]) + (partB[0] + partB[1]);
        acc = fmaf(cwgt, part + 0.5f * (1.f + sval), acc);
    }

    acc += __shfl_xor(acc, 32);
    if (l < 32) atomicAdd(&out[(size_t)b * S_ + sidx], acc);
}

// ---------------------------------------------------------------------------
extern "C" void kernel_launch(void* const* d_in, const int* in_sizes, int n_in,
                              void* d_out, int out_size, void* d_ws, size_t ws_size,
                              hipStream_t stream) {
    (void)in_sizes; (void)n_in; (void)out_size; (void)d_ws; (void)ws_size;

    const float* packed  = (const float*)d_in[0];
    const float* samples = (const float*)d_in[1];
    const float* fc1w = (const float*)d_in[2];
    const float* fc1b = (const float*)d_in[3];
    const float* bw1  = (const float*)d_in[4];
    const float* bb1  = (const float*)d_in[5];
    const float* gw1  = (const float*)d_in[6];
    const float* gb1  = (const float*)d_in[7];
    const float* rw1  = (const float*)d_in[8];
    const float* rb1  = (const float*)d_in[9];
    const float* bw2  = (const float*)d_in[10];
    const float* bb2  = (const float*)d_in[11];
    const float* gw2  = (const float*)d_in[12];
    const float* gb2  = (const float*)d_in[13];
    const float* rw2  = (const float*)d_in[14];
    const float* rb2  = (const float*)d_in[15];
    const float* bw3  = (const float*)d_in[16];
    const float* bb3  = (const float*)d_in[17];
    const float* gw3  = (const float*)d_in[18];
    const float* gb3  = (const float*)d_in[19];
    const float* fc2w = (const float*)d_in[20];
    const float* fc2b = (const float*)d_in[21];
    float* out = (float*)d_out;

    ldif_fused<<<768, 256, 0, stream>>>(
        packed, samples, fc1w, fc1b,
        bw1, bb1, gw1, gb1, rb1, rw1,
        bw2, bb2, gw2, gb2, rw2, rb2,
        bw3, bb3, gw3, gb3, fc2w, fc2b, out);
}

// Round 19
// 32.526 us; speedup vs baseline: 12.2935x; 12.2935x over previous
//
#include <hip/hip_runtime.h>
#include <math.h>

#define B_   4
#define EC_  32
#define E_   48
#define S_   2048
#define F_   128

typedef __attribute__((ext_vector_type(2)))  float f32x2;
typedef __attribute__((ext_vector_type(8)))  short short8;
typedef __attribute__((ext_vector_type(4)))  float f32x4;
typedef __attribute__((ext_vector_type(16))) float f32x16;

// ---- global prepacked parameter parks -------------------------------------
// A1: GEMM1 weights (rfc1_w) as 32x32x16 A-fragments, transposed GEMM:
//   A1frag[MT][ks][lane][j] = bf16( rw1[f_in][f_out] )
//   f_out = MT*32 + (lane&31)
//   f_in  = (ks>>1)*32 + (ks&1)*16 + ((j>>2)&1)*8 + (j&3) + (lane>>5)*4
__device__ __align__(16) short g_A1[4 * 8 * 64 * 8];     // 32 KB

// per-be park (floats):
// [0..127]=gamma2', [128..255]=beta2', [256..383]=u, [384..399]=geo,
// [400..403]=w3c (w3[0..2], w3b+cbeta), [416..1439]=A0 frags (2048 shorts)
#define PKF2 1440
__device__ __align__(16) float g_bepark[B_ * E_ * PKF2];

static __device__ __forceinline__ short f2bf(float x) {
    unsigned u = __float_as_uint(x);
    unsigned r = (u + 0x7FFFu + ((u >> 16) & 1u)) >> 16;   // RNE
    return (short)r;
}

static __device__ __forceinline__ f32x2 pkfma(f32x2 a, f32x2 b, f32x2 c) {
    f32x2 d;
    asm("v_pk_fma_f32 %0, %1, %2, %3" : "=v"(d) : "v"(a), "v"(b), "v"(c));
    return d;
}

// ---------------------------------------------------------------------------
// Kernel A: blocks 0..191  -> per-(b,e) CBN GEMVs + folds + A0 frags + geo
//           blocks 192..195 -> rfc1_w -> A1 fragment packing
//           blocks 196..199 -> zero d_out (so main can atomicAdd, no memset)
// grid = 200 x 512
// ---------------------------------------------------------------------------
__global__ __launch_bounds__(512) void precompute_kernel(
    const float* __restrict__ packed,
    const float* __restrict__ fc1w, const float* __restrict__ fc1b,
    const float* __restrict__ bw1, const float* __restrict__ bb1,
    const float* __restrict__ gw1, const float* __restrict__ gb1,
    const float* __restrict__ rb1g, const float* __restrict__ rw1,
    const float* __restrict__ bw2, const float* __restrict__ bb2,
    const float* __restrict__ gw2, const float* __restrict__ gb2,
    const float* __restrict__ rw2, const float* __restrict__ rb2g,
    const float* __restrict__ bw3, const float* __restrict__ bb3,
    const float* __restrict__ gw3, const float* __restrict__ gb3,
    const float* __restrict__ fc2w, const float* __restrict__ fc2b,
    float* __restrict__ out)
{
    const int be = blockIdx.x;

    if (be >= 196) {                       // ---- zero-out path ----
        const int q = be - 196;
        f32x4 z = {0.f, 0.f, 0.f, 0.f};
        *(f32x4*)&out[(size_t)q * 2048 + threadIdx.x * 4] = z;
        return;
    }
    if (be >= 192) {                       // ---- A1 packing path ----
        const int unit = (be - 192) * 8 + (threadIdx.x >> 6);   // 0..31
        const int l  = threadIdx.x & 63;
        const int MT = unit >> 3;
        const int ks = unit & 7;
        const int fo = MT * 32 + (l & 31);
        const int q1 = l >> 5;
        short8 v;
        #pragma unroll
        for (int j = 0; j < 8; ++j) {
            const int fi = (ks >> 1) * 32 + (ks & 1) * 16 + ((j >> 2) & 1) * 8 +
                           (j & 3) + q1 * 4;
            v[j] = f2bf(rw1[fi * F_ + fo]);
        }
        *(short8*)&g_A1[((MT * 8 + ks) * 64 + l) * 8] = v;
        return;
    }

    const int b  = be / E_;
    const int e  = be - b * E_;
    const int ec = (e < EC_) ? e : (e - EC_);
    const float* pv = packed + (size_t)(b * EC_ + ec) * 138;
    float* P = g_bepark + (size_t)be * PKF2;

    __shared__ float emb[F_];
    __shared__ float part[6][4][F_];     // 12 KB
    __shared__ float g3s[F_];
    __shared__ float wred[2][5];

    const int t = threadIdx.x & 127;
    const int h = threadIdx.x >> 7;      // 0..3 (k-quarter)
    if (h == 0) emb[t] = pv[10 + t];
    __syncthreads();

    float a0 = 0.f, a1 = 0.f, a2 = 0.f, a3 = 0.f, a4 = 0.f, a5 = 0.f;
    for (int k = h * 32; k < h * 32 + 32; ++k) {
        const float ek = emb[k];
        a0 = fmaf(ek, bw1[k * F_ + t], a0);
        a1 = fmaf(ek, gw1[k * F_ + t], a1);
        a2 = fmaf(ek, bw2[k * F_ + t], a2);
        a3 = fmaf(ek, gw2[k * F_ + t], a3);
        a4 = fmaf(ek, bw3[k * F_ + t], a4);
        a5 = fmaf(ek, gw3[k * F_ + t], a5);
    }
    part[0][h][t] = a0; part[1][h][t] = a1; part[2][h][t] = a2;
    part[3][h][t] = a3; part[4][h][t] = a4; part[5][h][t] = a5;
    __syncthreads();

    const float inv = 0.99999500003749984f;   // 1/sqrt(1+1e-5)
    if (h == 0) {
        const float sb1 = part[0][0][t] + part[0][1][t] + part[0][2][t] + part[0][3][t];
        const float sg1 = part[1][0][t] + part[1][1][t] + part[1][2][t] + part[1][3][t];
        const float sb2 = part[2][0][t] + part[2][1][t] + part[2][2][t] + part[2][3][t];
        const float sg2 = part[3][0][t] + part[3][1][t] + part[3][2][t] + part[3][3][t];
        const float sb3 = part[4][0][t] + part[4][1][t] + part[4][2][t] + part[4][3][t];
        const float sg3 = part[5][0][t] + part[5][1][t] + part[5][2][t] + part[5][3][t];

        const float g1p = (sg1 + gb1[t]) * inv;
        const float b1  =  sb1 + bb1[t];
        const float g2p = (sg2 + gb2[t]) * inv;
        const float b2p = fmaf(g2p, rb1g[t], sb2 + bb2[t]);   // rb1 folded
        const float g3  = (sg3 + gb3[t]) * inv * fc2w[t];     // fc2 folded

        P[0 * F_ + t] = g2p;
        P[1 * F_ + t] = b2p;
        g3s[t] = g3;

        // A0 fragment (fc1 + CBN1 folded), 32x32x16 A-layout, k slots 0..3
        const float w0p = g1p * fc1w[t];
        const float w1p = g1p * fc1w[F_ + t];
        const float w2p = g1p * fc1w[2 * F_ + t];
        const float pbp = fmaf(g1p, fc1b[t], b1);
        short* A0 = (short*)(P + 416);
        const int MTl = t >> 5, fl = t & 31;
        short8 v  = {f2bf(w0p), f2bf(w1p), f2bf(w2p), f2bf(pbp), 0, 0, 0, 0};
        short8 zz = {0, 0, 0, 0, 0, 0, 0, 0};
        *(short8*)&A0[(MTl * 64 + fl) * 8]      = v;
        *(short8*)&A0[(MTl * 64 + 32 + fl) * 8] = zz;

        // 2-wave shfl reduction of cbeta & w3 partials (exact fp32 fold)
        float cbv  = (sb3 + bb3[t]) * fc2w[t] + g3 * rb2g[t];  // beta3+rb2 fold
        float w30v = g3 * w0p;
        float w31v = g3 * w1p;
        float w32v = g3 * w2p;
        float w3bv = g3 * pbp;
        #pragma unroll
        for (int off = 32; off >= 1; off >>= 1) {
            cbv  += __shfl_xor(cbv,  off);
            w30v += __shfl_xor(w30v, off);
            w31v += __shfl_xor(w31v, off);
            w32v += __shfl_xor(w32v, off);
            w3bv += __shfl_xor(w3bv, off);
        }
        if ((t & 63) == 0) {
            const int wv = t >> 6;
            wred[wv][0] = cbv;  wred[wv][1] = w30v; wred[wv][2] = w31v;
            wred[wv][3] = w32v; wred[wv][4] = w3bv;
        }
    } else if (threadIdx.x == 256) {
        // geometry (runs concurrently with the h==0 fold section)
        const float sx = fmaxf(pv[4], 1e-4f);
        const float sy = fmaxf(pv[5], 1e-4f);
        const float sz = fmaxf(pv[6], 1e-4f);
        const float ar = pv[7], ap = pv[8], ay = pv[9];
        const float cr = cosf(ar), sr = sinf(ar);
        const float cp = cosf(ap), sp = sinf(ap);
        const float cyw = cosf(ay), syw = sinf(ay);
        float* g = P + 384;
        g[0] = pv[0]; g[1] = pv[1]; g[2] = pv[2]; g[3] = pv[3];
        g[4] = 1.f / sx; g[5] = 1.f / sy; g[6] = 1.f / sz;
        g[7]  = cyw * cp;  g[8]  = cyw * sp * sr - syw * cr;  g[9]  = cyw * sp * cr + syw * sr;
        g[10] = syw * cp;  g[11] = syw * sp * sr + cyw * cr;  g[12] = syw * sp * cr - cyw * sr;
        g[13] = -sp;       g[14] = cp * sr;                   g[15] = cp * cr;
    }
    __syncthreads();

    // u[k] = sum_f g3[f] * rw2[k][f]   (split over h quarters) -> part[5]
    {
        float ua = 0.f;
        const float* wrow = rw2 + (size_t)t * F_ + h * 32;
        #pragma unroll
        for (int f4 = 0; f4 < 32; f4 += 4) {
            const f32x4 wv = *(const f32x4*)&wrow[f4];
            const int fb = h * 32 + f4;
            ua = fmaf(wv[0], g3s[fb + 0], ua);
            ua = fmaf(wv[1], g3s[fb + 1], ua);
            ua = fmaf(wv[2], g3s[fb + 2], ua);
            ua = fmaf(wv[3], g3s[fb + 3], ua);
        }
        part[5][h][t] = ua;
    }
    __syncthreads();

    if (h == 0)
        P[2 * F_ + t] = part[5][0][t] + part[5][1][t] + part[5][2][t] + part[5][3][t];

    if (threadIdx.x == 0) {
        P[400] = wred[0][1] + wred[1][1];
        P[401] = wred[0][2] + wred[1][2];
        P[402] = wred[0][3] + wred[1][3];
        P[403] = (wred[0][4] + wred[1][4]) + fc2b[0] + wred[0][0] + wred[1][0];
    }
}

// ---------------------------------------------------------------------------
// Kernel B: main. grid = 4b x 16seg x 12eq = 768 blocks x 256 threads
// (4 waves). 768 = 256 CU x 3 blocks/CU: exact single-shot at 3 waves/SIMD
// (__launch_bounds__(256,3) caps VGPR at 170; live set ~130 after the
// early-d0-death restructure: d0[MT] is computed, repacked into 2 B-frags,
// and dies before the next MT). 4 elements per block.
// ---------------------------------------------------------------------------
__global__ __launch_bounds__(256, 3) void ldif_main(
    const float* __restrict__ samples, float* __restrict__ out)
{
    const int bid = blockIdx.x;
    const int eq  = bid % 12;
    const int r12 = bid / 12;
    const int seg = r12 & 15;
    const int b   = r12 >> 4;

    __shared__ __align__(16) short lsA1[4 * 8 * 64 * 8];   // 32 KB
    __shared__ __align__(16) float lsPar[4 * 416];         // 6.5 KB

    const int tid = threadIdx.x;

    // ---- stage A1 (32 KB) + 4 elements' params into LDS ----
    {
        const f32x4* src = (const f32x4*)g_A1;
        f32x4* dst = (f32x4*)lsA1;
        #pragma unroll
        for (int i = 0; i < 8; ++i) dst[i * 256 + tid] = src[i * 256 + tid];
    }
    for (int i = tid; i < 416; i += 256) {
        const int ei = i / 104;
        const int o4 = i - ei * 104;
        ((f32x4*)lsPar)[ei * 104 + o4] =
            *(const f32x4*)&g_bepark[(size_t)(b * E_ + eq * 4 + ei) * PKF2 + o4 * 4];
    }
    __syncthreads();

    const int w   = tid >> 6;           // wave 0..3 = sample chunk
    const int l   = tid & 63;
    const int q1  = l >> 5;
    const int l31 = l & 31;
    const int sidx = seg * 128 + w * 32 + l31;
    const f32x16 z16 = {0.f,0.f,0.f,0.f,0.f,0.f,0.f,0.f,
                        0.f,0.f,0.f,0.f,0.f,0.f,0.f,0.f};

    const float* sp = samples + ((size_t)b * S_ + sidx) * 3;
    const float xs = sp[0], ys = sp[1], zs0 = sp[2];

    float acc = 0.f;

    for (int ee = 0; ee < 4; ++ee) {
        const int e  = eq * 4 + ee;
        const int be = b * E_ + e;
        const float* Pl = &lsPar[ee * 416];
        const float* gg = Pl + 384;
        const float* w3 = Pl + 400;
        const float* Pg = g_bepark + (size_t)be * PKF2;   // A0 frags only

        // ---- geometry (params from LDS, broadcast) ----
        float cwgt, sval;
        union { short8 s8; unsigned u[4]; } b0u;
        b0u.u[0] = 0; b0u.u[1] = 0; b0u.u[2] = 0; b0u.u[3] = 0;
        {
            const float zz = (e >= EC_) ? -zs0 : zs0;
            const float dx = xs - gg[1], dy = ys - gg[2], dz = zz - gg[3];
            const float l0 = (dx * gg[7] + dy * gg[10] + dz * gg[13]) * gg[4];
            const float l1 = (dx * gg[8] + dy * gg[11] + dz * gg[14]) * gg[5];
            const float l2 = (dx * gg[9] + dy * gg[12] + dz * gg[15]) * gg[6];
            cwgt = gg[0] * __expf(-0.5f * (l0 * l0 + l1 * l1 + l2 * l2));
            sval = fmaf(l0, w3[0], fmaf(l1, w3[1], fmaf(l2, w3[2], w3[3])));
            if (q1 == 0) {
                const float one = 1.0f;
                unsigned p01, p23;
                asm("v_cvt_pk_bf16_f32 %0, %1, %2" : "=v"(p01) : "v"(l0), "v"(l1));
                asm("v_cvt_pk_bf16_f32 %0, %1, %2" : "=v"(p23) : "v"(l2), "v"(one));
                b0u.u[0] = p01; b0u.u[1] = p23;
            }
        }
        const short8 b0 = b0u.s8;

        // ---- fc1+CBN1 MFMA interleaved with GEMM1 (early-d0-death):
        //      d0[MTs] -> repack ks=2*MTs, 2*MTs+1 -> d0 dies.
        const short* A0g = (const short*)(Pg + 416);
        f32x16 d1[4];
        #pragma unroll
        for (int MT = 0; MT < 4; ++MT) d1[MT] = z16;

        #pragma unroll
        for (int MTs = 0; MTs < 4; ++MTs) {
            const short8 a0 = *(const short8*)&A0g[(MTs * 64 + l) * 8];
            const f32x16 d0 = __builtin_amdgcn_mfma_f32_32x32x16_bf16(a0, b0, z16, 0, 0, 0);
            #pragma unroll
            for (int kk = 0; kk < 2; ++kk) {
                const int ks = MTs * 2 + kk;
                union { short8 s8; unsigned u[4]; } b1u;
                #pragma unroll
                for (int jj = 0; jj < 4; ++jj) {
                    const int j0 = jj * 2;
                    const int r0 = (j0 & 3) + 4 * ((j0 >> 2) & 1) + 8 * kk;
                    const float v0 = fmaxf(d0[r0], 0.f);
                    const float v1 = fmaxf(d0[r0 + 1], 0.f);
                    asm("v_cvt_pk_bf16_f32 %0, %1, %2" : "=v"(b1u.u[jj]) : "v"(v0), "v"(v1));
                }
                const short8 b1 = b1u.s8;
                #pragma unroll
                for (int MT = 0; MT < 4; ++MT) {
                    const short8 a = *(const short8*)&lsA1[((MT * 8 + ks) * 64 + l) * 8];
                    d1[MT] = __builtin_amdgcn_mfma_f32_32x32x16_bf16(a, b1, d1[MT], 0, 0, 0);
                }
            }
        }

        // ---- epilogue: sum_k relu(g2*d1+b2')*u via pk_fma, params from LDS ----
        f32x2 partA = {0.f, 0.f};
        f32x2 partB = {0.f, 0.f};
        #pragma unroll
        for (int MT = 0; MT < 4; ++MT) {
            #pragma unroll
            for (int c = 0; c < 4; ++c) {
                const int fb = MT * 32 + c * 8 + q1 * 4;
                const f32x4 g2 = *(const f32x4*)&Pl[fb];
                const f32x4 b2 = *(const f32x4*)&Pl[128 + fb];
                const f32x4 uu = *(const f32x4*)&Pl[256 + fb];
                f32x2 g2a = {g2[0], g2[1]}, g2b = {g2[2], g2[3]};
                f32x2 b2a = {b2[0], b2[1]}, b2b = {b2[2], b2[3]};
                f32x2 uua = {uu[0], uu[1]}, uub = {uu[2], uu[3]};
                f32x2 d1a = {d1[MT][c * 4 + 0], d1[MT][c * 4 + 1]};
                f32x2 d1b = {d1[MT][c * 4 + 2], d1[MT][c * 4 + 3]};
                f32x2 tta = pkfma(g2a, d1a, b2a);
                f32x2 ttb = pkfma(g2b, d1b, b2b);
                tta[0] = fmaxf(tta[0], 0.f); tta[1] = fmaxf(tta[1], 0.f);
                ttb[0] = fmaxf(ttb[0], 0.f); ttb[1] = fmaxf(ttb[1], 0.f);
                partA = pkfma(tta, uua, partA);
                partB = pkfma(ttb, uub, partB);
            }
        }
        const float part = (partA[0] + partA[1]) + (partB[0] + partB[1]);
        // half-share: each q1-half adds its part + half of the affine term
        acc = fmaf(cwgt, part + 0.5f * (1.f + sval), acc);
    }

    acc += __shfl_xor(acc, 32);
    if (l < 32) atomicAdd(&out[(size_t)b * S_ + sidx], acc);
}

// ---------------------------------------------------------------------------
extern "C" void kernel_launch(void* const* d_in, const int* in_sizes, int n_in,
                              void* d_out, int out_size, void* d_ws, size_t ws_size,
                              hipStream_t stream) {
    (void)in_sizes; (void)n_in; (void)out_size; (void)d_ws; (void)ws_size;

    const float* packed  = (const float*)d_in[0];
    const float* samples = (const float*)d_in[1];
    const float* fc1w = (const float*)d_in[2];
    const float* fc1b = (const float*)d_in[3];
    const float* bw1  = (const float*)d_in[4];
    const float* bb1  = (const float*)d_in[5];
    const float* gw1  = (const float*)d_in[6];
    const float* gb1  = (const float*)d_in[7];
    const float* rw1  = (const float*)d_in[8];
    const float* rb1  = (const float*)d_in[9];
    const float* bw2  = (const float*)d_in[10];
    const float* bb2  = (const float*)d_in[11];
    const float* gw2  = (const float*)d_in[12];
    const float* gb2  = (const float*)d_in[13];
    const float* rw2  = (const float*)d_in[14];
    const float* rb2  = (const float*)d_in[15];
    const float* bw3  = (const float*)d_in[16];
    const float* bb3  = (const float*)d_in[17];
    const float* gw3  = (const float*)d_in[18];
    const float* gb3  = (const float*)d_in[19];
    const float* fc2w = (const float*)d_in[20];
    const float* fc2b = (const float*)d_in[21];
    float* out = (float*)d_out;

    precompute_kernel<<<200, 512, 0, stream>>>(
        packed, fc1w, fc1b,
        bw1, bb1, gw1, gb1, rb1, rw1,
        bw2, bb2, gw2, gb2, rw2, rb2,
        bw3, bb3, gw3, gb3, fc2w, fc2b, out);

    ldif_main<<<768, 256, 0, stream>>>(samples, out);
}